// Round 13
// baseline (96.356 us; speedup 1.0000x reference)
//
#include <hip/hip_runtime.h>

// B=8, C=128, H=W=64 -> N=4096 tokens/batch. d_qk=32.
// R13 = R12 with K-staging LDS dest FIXED: wave-uniform base w*512 (was
// accidentally w*1024, clobbering V and leaving K keys 16..31 unstaged -> NaN).
// attn: KT=32, 128-thread blocks (2 waves x 32q), grid 2048 -> 8 blocks/CU
// (20KB LDS). Swapped QK^T + key-permuted V + pre-swizzled global_load_lds +
// 2-phase dbuf + ones-column-MFMA l. lnqkv/wconv/out_kernel = R11.

#define NB 8
#define CCH 128
#define NTOK 4096
#define DQK 32
#define KT 32

typedef __attribute__((ext_vector_type(8))) short bf16x8;
typedef __attribute__((ext_vector_type(4))) float f32x4;
typedef unsigned short u16;
typedef unsigned int u32;

static __device__ __forceinline__ f32x4 mfma16(bf16x8 a, bf16x8 b, f32x4 c) {
  return __builtin_amdgcn_mfma_f32_16x16x32_bf16(a, b, c, 0, 0, 0);
}
static __device__ __forceinline__ u16 f2bf(float f) {
  union { float f; u32 u; } cv; cv.f = f;
  u32 u = cv.u;
  u += 0x7fffu + ((u >> 16) & 1u);
  return (u16)(u >> 16);
}
static __device__ __forceinline__ float bf2f(u16 v) {
  union { u32 u; float f; } cv; cv.u = ((u32)v) << 16;
  return cv.f;
}
static __device__ __forceinline__ u32 cvtpk(float lo, float hi) {
  u32 d;
  asm("v_cvt_pk_bf16_f32 %0, %1, %2" : "=v"(d) : "v"(lo), "v"(hi));
  return d;
}
static __device__ __forceinline__ void gload16(const void* g, void* l) {
  __builtin_amdgcn_global_load_lds(
      (const __attribute__((address_space(1))) void*)g,
      (__attribute__((address_space(3))) void*)l, 16, 0, 0);
}

// ---------------- kernel 0: weights -> bf16 [320][128] ----------------------
__global__ __launch_bounds__(256) void wconv_kernel(
    const float* __restrict__ Wq, const float* __restrict__ Wk,
    const float* __restrict__ Wv, const float* __restrict__ Wo,
    u16* __restrict__ wcomb) {
  int idx = blockIdx.x * 256 + threadIdx.x;
  int r = idx >> 7;
  float v;
  if (r < 32)        v = Wq[idx];
  else if (r < 64)   v = Wk[idx - 4096];
  else if (r < 192)  v = Wv[idx - 8192];
  else               v = Wo[idx - 24576];
  wcomb[idx] = f2bf(v);
}

// ---------------- kernel 1: fused LayerNorm + QKV projection ----------------
__global__ __launch_bounds__(256) void lnqkv_kernel(
    const float* __restrict__ x, const float* __restrict__ gamma,
    const float* __restrict__ beta, const u16* __restrict__ wcomb,
    u16* __restrict__ Qg, u16* __restrict__ Kg, u16* __restrict__ Vt) {
  __shared__ float tile[128][64];
  __shared__ float red[2][4][64];
  __shared__ u16   xt[64][130];
  int t = threadIdx.x;
  int lane = t & 63, cq = t >> 6;
  int b = blockIdx.x >> 6;
  int posb = (blockIdx.x & 63) << 6;
  const float* xb = x + ((size_t)b * CCH) * NTOK + posb;
  for (int i = 0; i < 32; ++i) {
    int c = cq * 32 + i;
    tile[c][lane] = xb[(size_t)c * NTOK + lane];
  }
  __syncthreads();
  float s = 0.f, s2 = 0.f;
  for (int i = 0; i < 32; ++i) {
    float v = tile[cq * 32 + i][lane];
    s += v; s2 += v * v;
  }
  red[0][cq][lane] = s; red[1][cq][lane] = s2;
  __syncthreads();
  float mu  = (red[0][0][lane] + red[0][1][lane] + red[0][2][lane] + red[0][3][lane]) * (1.f / 128.f);
  float ex2 = (red[1][0][lane] + red[1][1][lane] + red[1][2][lane] + red[1][3][lane]) * (1.f / 128.f);
  float rstd = rsqrtf(ex2 - mu * mu + 1e-5f);
  for (int i = 0; i < 32; ++i) {
    int c = cq * 32 + i;
    float v = (tile[c][lane] - mu) * rstd * gamma[c] + beta[c];
    xt[lane][c] = f2bf(v);
  }
  __syncthreads();
  int w = t >> 6, row16 = lane & 15, kgrp = lane >> 4;
  bf16x8 af[4];
  for (int ks = 0; ks < 4; ++ks)
    af[ks] = *(const bf16x8*)&xt[w * 16 + row16][ks * 32 + kgrp * 8];
  f32x4 zero = {0.f, 0.f, 0.f, 0.f};
  f32x4 acc[12];
  for (int nt = 0; nt < 12; ++nt) {
    acc[nt] = zero;
    for (int ks = 0; ks < 4; ++ks) {
      bf16x8 bf = *(const bf16x8*)&wcomb[(size_t)(nt * 16 + row16) * CCH + ks * 32 + kgrp * 8];
      acc[nt] = mfma16(af[ks], bf, acc[nt]);
    }
  }
  int tok0 = b * NTOK + posb;
  for (int nt = 0; nt < 12; ++nt) {
    int col = nt * 16 + row16;
    for (int r = 0; r < 4; ++r) {
      int token = tok0 + w * 16 + kgrp * 4 + r;
      if (col < 32) {
        Qg[(size_t)token * DQK + col] = f2bf(acc[nt][r] * 1.44269504f);
      } else if (col < 64) {
        Kg[(size_t)token * DQK + (col - 32)] = f2bf(acc[nt][r]);
      } else {
        int tl = token & (NTOK - 1);
        int kp = (tl & ~31) | ((tl & 12) << 1) | ((tl & 16) >> 2) | (tl & 3);
        Vt[((size_t)b * CCH + (col - 64)) * NTOK + kp] = f2bf(acc[nt][r]);
      }
    }
  }
}

// ---------------- kernel 2: flash attention ---------------------------------
// 2 waves x 32q = 64 q/block; KT=32; split-K(NS); grid 512*NS = 2048 (NS=4).
// LDS per buf (10KB): K 1024 u16 (16 key-pair rows x 8 slots of 8 u16,
// phys slot = logical ^ (row&7)); V 4096 u16 (128 ch x 4 slots of 16B,
// phys = s ^ ((c>>1)&3)). Staging: pre-swizzled global source + LINEAR
// wave-uniform LDS dest (K: w*512 + lane*16B; V: 1024 + j*1024 + w*512).
template <int NS>
__global__ __launch_bounds__(128, 4) void attn_kernel(
    const u16* __restrict__ Qg, const u16* __restrict__ Kg,
    const u16* __restrict__ Vt, u16* __restrict__ Op,
    float* __restrict__ lp) {
  __shared__ u16 lds[2][5120];    // per buf: K 1024 u16 + V 4096 u16 = 10KB
  constexpr int KSEG = NTOK / NS;
  constexpr int NTILE = KSEG / KT;
  int t = threadIdx.x;
  int w = t >> 6, lane = t & 63;
  int row16 = lane & 15, kgrp = lane >> 4;

  int cpx = (512 * NS) >> 3;
  int logical = (blockIdx.x & 7) * cpx + (blockIdx.x >> 3);  // XCD-chunked
  int qblk = logical & 63;
  int part = (logical >> 6) & (NS - 1);
  int b = logical / (64 * NS);
  int q0 = qblk * 64;
  int kt0 = part * KSEG;

  const u16* Qb = Qg + ((size_t)(b * NTOK + q0 + w * 32)) * DQK;
  bf16x8 qf0 = *(const bf16x8*)&Qb[(size_t)row16 * DQK + kgrp * 8];
  bf16x8 qf1 = *(const bf16x8*)&Qb[(size_t)(16 + row16) * DQK + kgrp * 8];

  bf16x8 ones_b;
  {
    short val = (row16 == 0) ? (short)0x3F80 : (short)0;
    for (int j = 0; j < 8; ++j) ones_b[j] = val;
  }

  // K staging source (inverse-XOR of key-pair-row swizzle), 1 gload/thread:
  // phys slot = t; row pr=t>>3, d=t&7; logical=d^(pr&7); key=pr*2+(logical>>2).
  int pr = t >> 3, d8 = t & 7;
  int korig = d8 ^ (pr & 7);
  int kkey = pr * 2 + (korig >> 2);
  int kfs = korig & 3;
  const u16* ksrc = Kg + (size_t)(b * NTOK + kt0 + kkey) * DQK + kfs * 8;
  // V staging source, 4 gloads/thread: phys g=j*128+t; c=j*32+(t>>2), d=t&3;
  // logical s = d ^ ((c>>1)&3) = d ^ ((t>>3)&3).
  int cV = t >> 2;
  int sV = (t & 3) ^ ((t >> 3) & 3);
  const u16* vsrc = Vt + ((size_t)b * CCH + cV) * NTOK + kt0 + sV * 8;

  f32x4 zero = {0.f, 0.f, 0.f, 0.f};
  f32x4 o0[8], o1[8], ol0, ol1;
#pragma unroll
  for (int i = 0; i < 8; ++i) { o0[i] = zero; o1[i] = zero; }
  ol0 = zero; ol1 = zero;

  auto stage = [&](int bi, int tile) {
    const u16* kp_ = ksrc + (size_t)tile * (KT * DQK);
    gload16(kp_, &lds[bi][w * 512]);                 // FIX: wave-uniform w*512
    const u16* vp_ = vsrc + tile * KT;
#pragma unroll
    for (int j = 0; j < 4; ++j)
      gload16(vp_ + (size_t)j * (32 * NTOK),
              &lds[bi][1024 + j * 1024 + w * 512]);
  };

  auto compute = [&](int bi) {
    const u16* kb = &lds[bi][0];
    const u16* vb = &lds[bi][1024];
    f32x4 sa0[2], sa1[2];
#pragma unroll
    for (int nt = 0; nt < 2; ++nt) {
      int slot = (nt * 8 + (row16 >> 1)) * 8 +
                 ((((row16 & 1) << 2) + kgrp) ^ (row16 >> 1));
      bf16x8 kf = *(const bf16x8*)&kb[slot * 8];
      sa0[nt] = mfma16(kf, qf0, zero);
      sa1[nt] = mfma16(kf, qf1, zero);
    }
#pragma unroll
    for (int nt = 0; nt < 2; ++nt)
      for (int r = 0; r < 4; ++r) {
        sa0[nt][r] = __builtin_amdgcn_exp2f(sa0[nt][r]);
        sa1[nt][r] = __builtin_amdgcn_exp2f(sa1[nt][r]);
      }
    union PU { u32 d[4]; bf16x8 v; };
    PU pf0, pf1;
    pf0.d[0] = cvtpk(sa0[0][0], sa0[0][1]);
    pf0.d[1] = cvtpk(sa0[0][2], sa0[0][3]);
    pf0.d[2] = cvtpk(sa0[1][0], sa0[1][1]);
    pf0.d[3] = cvtpk(sa0[1][2], sa0[1][3]);
    pf1.d[0] = cvtpk(sa1[0][0], sa1[0][1]);
    pf1.d[1] = cvtpk(sa1[0][2], sa1[0][3]);
    pf1.d[2] = cvtpk(sa1[1][0], sa1[1][1]);
    pf1.d[3] = cvtpk(sa1[1][2], sa1[1][3]);
    ol0 = mfma16(pf0.v, ones_b, ol0);
    ol1 = mfma16(pf1.v, ones_b, ol1);
#pragma unroll
    for (int ntc = 0; ntc < 8; ++ntc) {
      int c = ntc * 16 + row16;
      int vslot = c * 4 + (kgrp ^ ((c >> 1) & 3));
      bf16x8 vf = *(const bf16x8*)&vb[vslot * 8];
      o0[ntc] = mfma16(pf0.v, vf, o0[ntc]);
      o1[ntc] = mfma16(pf1.v, vf, o1[ntc]);
    }
  };

  stage(0, 0);
  asm volatile("s_waitcnt vmcnt(0)" ::: "memory");
  __builtin_amdgcn_s_barrier();
  int cur = 0;
  for (int tile = 0; tile < NTILE - 1; ++tile) {
    stage(cur ^ 1, tile + 1);
    compute(cur);
    asm volatile("s_waitcnt vmcnt(0)" ::: "memory");
    __builtin_amdgcn_s_barrier();
    cur ^= 1;
  }
  compute(cur);

  // epilogue: write unnormalized partial O + l (R11 form)
  u16* Opw = Op + (size_t)part * (32768 * CCH);
  int tokb = b * NTOK + q0 + w * 32;
#pragma unroll
  for (int r = 0; r < 4; ++r) {
    int tk0 = tokb + kgrp * 4 + r;
    int tk1 = tokb + 16 + kgrp * 4 + r;
#pragma unroll
    for (int ntc = 0; ntc < 8; ++ntc) {
      Opw[(size_t)tk0 * CCH + ntc * 16 + row16] = f2bf(o0[ntc][r]);
      Opw[(size_t)tk1 * CCH + ntc * 16 + row16] = f2bf(o1[ntc][r]);
    }
  }
  if (row16 == 0) {
#pragma unroll
    for (int r = 0; r < 4; ++r) {
      lp[part * 32768 + tokb + kgrp * 4 + r] = ol0[r];
      lp[part * 32768 + tokb + 16 + kgrp * 4 + r] = ol1[r];
    }
  }
}

// ---------------- kernel 3: combine parts + Wo GEMM + bias + residual -------
__global__ __launch_bounds__(256) void out_kernel(
    const u16* __restrict__ Op, const float* __restrict__ lp, int ns,
    const u16* __restrict__ wcomb, const float* __restrict__ bo,
    const float* __restrict__ x, float* __restrict__ out) {
  int t = threadIdx.x;
  int w = t >> 6, lane = t & 63;
  int row16 = lane & 15, kgrp = lane >> 4;
  int tok0 = blockIdx.x * 64;
  int b = tok0 >> 12, tloc = tok0 & (NTOK - 1);
  int tokA = tok0 + w * 16 + row16;
  float lsum = 0.f;
  for (int j = 0; j < ns; ++j) lsum += lp[j * 32768 + tokA];
  float inv = 1.f / lsum;
  bf16x8 af[4];
  for (int ks = 0; ks < 4; ++ks) {
    float sum[8] = {0.f, 0.f, 0.f, 0.f, 0.f, 0.f, 0.f, 0.f};
    for (int j = 0; j < ns; ++j) {
      bf16x8 a = *(const bf16x8*)&Op[(size_t)j * (32768 * CCH) +
                                     (size_t)tokA * CCH + ks * 32 + kgrp * 8];
      for (int e = 0; e < 8; ++e) sum[e] += bf2f((u16)a[e]);
    }
    bf16x8 av;
    for (int e = 0; e < 8; ++e) av[e] = (short)f2bf(sum[e] * inv);
    af[ks] = av;
  }
  f32x4 zero = {0.f, 0.f, 0.f, 0.f};
  f32x4 acc[8];
  for (int nt = 0; nt < 8; ++nt) {
    acc[nt] = zero;
    for (int ks = 0; ks < 4; ++ks) {
      bf16x8 bf = *(const bf16x8*)&wcomb[(size_t)(192 + nt * 16 + row16) * CCH + ks * 32 + kgrp * 8];
      acc[nt] = mfma16(af[ks], bf, acc[nt]);
    }
  }
  for (int nt = 0; nt < 8; ++nt) {
    int cout = nt * 16 + row16;
    float bias = bo[cout];
    size_t base = ((size_t)b * CCH + cout) * NTOK + tloc + w * 16 + kgrp * 4;
    float4 xr = *(const float4*)&x[base];
    float4 ov;
    ov.x = acc[nt][0] + bias + xr.x;
    ov.y = acc[nt][1] + bias + xr.y;
    ov.z = acc[nt][2] + bias + xr.z;
    ov.w = acc[nt][3] + bias + xr.w;
    *(float4*)&out[base] = ov;
  }
}

extern "C" void kernel_launch(void* const* d_in, const int* in_sizes, int n_in,
                              void* d_out, int out_size, void* d_ws, size_t ws_size,
                              hipStream_t stream) {
  const float* x     = (const float*)d_in[0];
  const float* gamma = (const float*)d_in[1];
  const float* beta  = (const float*)d_in[2];
  const float* Wq    = (const float*)d_in[3];
  const float* Wk    = (const float*)d_in[4];
  const float* Wv    = (const float*)d_in[5];
  const float* Wo    = (const float*)d_in[6];
  const float* bo    = (const float*)d_in[7];
  float* out = (float*)d_out;

  unsigned char* ws = (unsigned char*)d_ws;
  u16* Qg    = (u16*)(ws);                  //  2 MB
  u16* Kg    = (u16*)(ws + 2097152);        //  2 MB
  u16* Vt    = (u16*)(ws + 4194304);        //  8 MB [8][128][4096] key-permuted
  u16* wcomb = (u16*)(ws + 12582912);       //  80 KB
  float* lp  = (float*)(ws + 12664832);     //  ns*128 KB
  u16* Op    = (u16*)(ws + 13189120);       //  ns*8 MB

  // split-4 needs 13189120 + 4*8388608 = 46743552 bytes of workspace
  int ns = (ws_size >= 46743552u) ? 4 : 2;

  wconv_kernel<<<160, 256, 0, stream>>>(Wq, Wk, Wv, Wo, wcomb);
  lnqkv_kernel<<<512, 256, 0, stream>>>(x, gamma, beta, wcomb, Qg, Kg, Vt);
  if (ns == 4)
    attn_kernel<4><<<2048, 128, 0, stream>>>(Qg, Kg, Vt, Op, lp);
  else
    attn_kernel<2><<<1024, 128, 0, stream>>>(Qg, Kg, Vt, Op, lp);
  out_kernel<<<512, 256, 0, stream>>>(Op, lp, ns, wcomb, bo, x, out);
}